// Round 1
// 111.342 us; speedup vs baseline: 1.0096x; 1.0096x over previous
//
#include <hip/hip_runtime.h>

// Sliding-window causal attention, B=2 H=8 S=4096 D=64, window=512.
// R6: 32-query waves on mfma_f32_32x32x16_bf16, swapped QK^T (S^T = K·Q^T),
//     in-register P transpose via v_cvt_pk_bf16_f32 + v_permlane32_swap_b32.
//     Ps LDS round-trip eliminated; K/V LDS re-read halved (4 waves/tile not 8).
//     K: triple-buffered global_load_lds, prefetch before the wait, vmcnt(2).
//     V: double-buffered, prefetch after the barrier.

#define NBATCH 2
#define NHEAD  8
#define SEQ    4096
#define DH     64
#define WIN    512
#define QT     128
#define KT     64

typedef __attribute__((ext_vector_type(4)))  float f32x4;
typedef __attribute__((ext_vector_type(16))) float f32x16;
typedef __attribute__((ext_vector_type(8)))  short bf16x8;
typedef unsigned short ushort_t;

__device__ __forceinline__ unsigned short f2bf(float f) {
  unsigned u = __builtin_bit_cast(unsigned, f);
  u += 0x7fffu + ((u >> 16) & 1u);
  return (unsigned short)(u >> 16);
}

__device__ __forceinline__ unsigned pkbf16(float a, float b) {
  unsigned d;
  asm("v_cvt_pk_bf16_f32 %0, %1, %2" : "=v"(d) : "v"(a), "v"(b));
  return d;
}

#define GLD16(gp, lp)                                                          \
  __builtin_amdgcn_global_load_lds(                                            \
      (const __attribute__((address_space(1))) unsigned int*)(gp),             \
      (__attribute__((address_space(3))) unsigned int*)(lp), 16, 0, 0)

// ---------------------------------------------------------------------------
// Prep: swizzled 8 KB 64x64 tile images. (row,blk) -> row*128 + ((blk^(row&7))<<4)
// K image: row = key, blk = d/8.   V image: row = d, blk = key/8.
// ---------------------------------------------------------------------------
__global__ __launch_bounds__(256) void prep_kernel(
    const float* __restrict__ Kg, const float* __restrict__ Vg,
    ushort_t* __restrict__ Kw, ushort_t* __restrict__ Vw)
{
  const int kt = blockIdx.x, bh = blockIdx.y;
  const size_t gbase = (size_t)bh * SEQ * DH + (size_t)kt * KT * DH;
  const size_t tbyte = ((size_t)bh * 64 + kt) * 8192;
  const int t = threadIdx.x;

  __shared__ float Vs[64][65];

  #pragma unroll
  for (int c = 0; c < 2; ++c) {
    int u = t + 256 * c, row = u >> 3, blk = u & 7;
    const float* src = Kg + gbase + row * DH + blk * 8;
    float4 a = *(const float4*)src;
    float4 b = *(const float4*)(src + 4);
    union { unsigned short us[8]; uint4 q; } o;
    o.us[0]=f2bf(a.x); o.us[1]=f2bf(a.y); o.us[2]=f2bf(a.z); o.us[3]=f2bf(a.w);
    o.us[4]=f2bf(b.x); o.us[5]=f2bf(b.y); o.us[6]=f2bf(b.z); o.us[7]=f2bf(b.w);
    *(uint4*)((char*)Kw + tbyte + row * 128 + ((blk ^ (row & 7)) << 4)) = o.q;
  }

  #pragma unroll
  for (int i = 0; i < 4; ++i) {
    int e = t + 256 * i, row = e >> 4, c4 = (e & 15) * 4;
    float4 v = *(const float4*)(Vg + gbase + row * DH + c4);
    Vs[row][c4 + 0] = v.x; Vs[row][c4 + 1] = v.y;
    Vs[row][c4 + 2] = v.z; Vs[row][c4 + 3] = v.w;
  }
  __syncthreads();

  #pragma unroll
  for (int c = 0; c < 2; ++c) {
    int u = t + 256 * c, d = u >> 3, blk = u & 7;
    union { unsigned short us[8]; uint4 q; } o;
    #pragma unroll
    for (int j = 0; j < 8; ++j) o.us[j] = f2bf(Vs[blk * 8 + j][d]);
    *(uint4*)((char*)Vw + tbyte + d * 128 + ((blk ^ (d & 7)) << 4)) = o.q;
  }
}

// ---------------------------------------------------------------------------
// Attention: one block = 128 queries of one (b,h); 4 waves x 32 queries.
// S^T = K·Q^T  (A = K-frag from LDS, B = Q-frag in regs), so each lane holds
// P[k-rows][q = lane&31]; exp + l-sum are lane-local; P A-frags for PV are
// built in-register (cvt_pk + permlane32_swap). O = P·V with A = P, B = V^T.
// ---------------------------------------------------------------------------
__global__ __launch_bounds__(256, 2) void swa_attn_kernel(
    const float* __restrict__ Qg, const ushort_t* __restrict__ Kw,
    const ushort_t* __restrict__ Vw, float* __restrict__ Og)
{
  const int qt = blockIdx.x, bh = blockIdx.y;
  const int q0 = qt * QT;
  const size_t base = (size_t)bh * SEQ * DH;
  const int t = threadIdx.x, w = t >> 6, l = t & 63;
  const int ql = l & 31, h = l >> 5;

  __shared__ ushort_t Ks[3][4096];   // 24 KB, triple buffer
  __shared__ ushort_t Vt[2][4096];   // 16 KB, double buffer
  // total 40 KB -> 2 blocks/CU (grid is exactly 2/CU)

  const size_t tile0 = ((size_t)bh * 64) * 8192;
  const int ldoff = w * 2048;        // this wave's 2 KB slice (wave-uniform)

  auto issueK = [&](int b, int kt) {
    const char* g = (const char*)Kw + tile0 + (size_t)kt * 8192 + ldoff;
    char* lp = (char*)&Ks[b][0] + ldoff;
    GLD16(g + l * 16, lp);
    GLD16(g + 1024 + l * 16, lp + 1024);
  };
  auto issueV = [&](int b, int kt) {
    const char* g = (const char*)Vw + tile0 + (size_t)kt * 8192 + ldoff;
    char* lp = (char*)&Vt[b][0] + ldoff;
    GLD16(g + l * 16, lp);
    GLD16(g + 1024 + l * 16, lp + 1024);
  };

  const int kt_hi = 2 * qt + 1;
  const int kt_lo = (2 * qt - 8 > 0) ? (2 * qt - 8) : 0;
  const int NT = kt_hi - kt_lo + 1;

  const int lo = q0 + 32 * w;   // this wave's min query row
  const int hi = lo + 31;       // max query row

  // ---- Q loads FIRST (oldest in vmcnt queue), then tile-0 DMA ----
  const float* qrow = Qg + base + (size_t)(lo + ql) * DH;
  float4 qa[4], qb[4];
  #pragma unroll
  for (int tf = 0; tf < 4; ++tf) {
    qa[tf] = *(const float4*)(qrow + 16 * tf + 8 * h);
    qb[tf] = *(const float4*)(qrow + 16 * tf + 8 * h + 4);
  }
  issueK(0, kt_hi);
  issueV(0, kt_hi);

  // Q as B-frags (scaled by 1/8): lane holds Q[lo+ql][d = 16*tf + 8*h + j]
  bf16x8 aq[4];
  #pragma unroll
  for (int tf = 0; tf < 4; ++tf) {
    union { unsigned short us[8]; bf16x8 v; } u;
    u.us[0]=f2bf(qa[tf].x*0.125f); u.us[1]=f2bf(qa[tf].y*0.125f);
    u.us[2]=f2bf(qa[tf].z*0.125f); u.us[3]=f2bf(qa[tf].w*0.125f);
    u.us[4]=f2bf(qb[tf].x*0.125f); u.us[5]=f2bf(qb[tf].y*0.125f);
    u.us[6]=f2bf(qb[tf].z*0.125f); u.us[7]=f2bf(qb[tf].w*0.125f);
    aq[tf] = u.v;
  }

  f32x16 acc[2];
  #pragma unroll
  for (int db = 0; db < 2; ++db)
    #pragma unroll
    for (int r = 0; r < 16; ++r) acc[db][r] = 0.0f;
  float lsum = 0.0f;

  int kmod = 0;  // i % 3
  for (int i = 0; i < NT; ++i) {
    const int kt = kt_hi - i;
    const int k0 = kt * KT;

    // K prefetch BEFORE the wait: vmcnt(2) drains everything older (this
    // tile's K+V) but leaves the 2 just-issued K chunks in flight.
    if (i + 1 < NT) {
      int kn = kmod + 1; if (kn == 3) kn = 0;
      issueK(kn, kt - 1);
      __asm__ __volatile__("s_waitcnt vmcnt(2)\n\ts_barrier" ::: "memory");
    } else {
      __asm__ __volatile__("s_waitcnt vmcnt(0)\n\ts_barrier" ::: "memory");
    }
    // V prefetch after the barrier (all waves finished tile i-1's compute).
    if (i + 1 < NT) issueV((i + 1) & 1, kt - 1);

    // ---- per-wave skip of fully-masked tiles (wave-uniform branch) ----
    const bool active = (k0 <= hi) && (k0 + KT - 1 >= lo - (WIN - 1));
    if (active) {
      const char* kbuf = (const char*)&Ks[kmod][0];
      const char* vbuf = (const char*)&Vt[i & 1][0];

      // ---- S^T = K Q^T : lane holds P[k = 32*kb + a(r) + 4h][q = lo+ql] ----
      f32x16 p[2];
      #pragma unroll
      for (int kb = 0; kb < 2; ++kb) {
        const int krow = 32 * kb + ql;
        const int ksz = krow & 7;
        f32x16 c;
        #pragma unroll
        for (int r = 0; r < 16; ++r) c[r] = 0.0f;
        #pragma unroll
        for (int tf = 0; tf < 4; ++tf) {
          bf16x8 ka = *(const bf16x8*)(kbuf + krow * 128 + (((2*tf + h) ^ ksz) << 4));
          c = __builtin_amdgcn_mfma_f32_32x32x16_bf16(ka, aq[tf], c, 0, 0, 0);
        }
        p[kb] = c;
      }

      // ---- exp (m=0 fixed shift, exact) + lane-local l-sum ----
      const int dbase = k0 - (lo + ql) + 4 * h;
      const bool needmask = (k0 + KT - 1 > lo) || (k0 < hi - (WIN - 1));
      if (needmask) {
        #pragma unroll
        for (int kb = 0; kb < 2; ++kb)
          #pragma unroll
          for (int r = 0; r < 16; ++r) {
            const int dji = dbase + 32 * kb + ((r & 3) + 8 * (r >> 2));
            float s = ((unsigned)(dji + (WIN - 1)) <= (unsigned)(WIN - 1))
                          ? p[kb][r] : -1e30f;
            float e = __expf(s);
            lsum += e;
            p[kb][r] = e;
          }
      } else {
        #pragma unroll
        for (int kb = 0; kb < 2; ++kb)
          #pragma unroll
          for (int r = 0; r < 16; ++r) {
            float e = __expf(p[kb][r]);
            lsum += e;
            p[kb][r] = e;
          }
      }

      // ---- in-register P transpose -> A-frags, fused with O += P V ----
      // frag t=2*kb+b: half h uses source regs 8b..8b+7; j0-3 from half 0,
      // j4-7 from half 1 -> two permlane32_swap per frag.
      #pragma unroll
      for (int kb = 0; kb < 2; ++kb) {
        #pragma unroll
        for (int b = 0; b < 2; ++b) {
          unsigned x0 = pkbf16(p[kb][8*b+0], p[kb][8*b+1]);
          unsigned x1 = pkbf16(p[kb][8*b+2], p[kb][8*b+3]);
          unsigned y0 = pkbf16(p[kb][8*b+4], p[kb][8*b+5]);
          unsigned y1 = pkbf16(p[kb][8*b+6], p[kb][8*b+7]);
          asm("v_permlane32_swap_b32 %0, %1" : "+v"(x0), "+v"(y0));
          asm("v_permlane32_swap_b32 %0, %1" : "+v"(x1), "+v"(y1));
          union { unsigned u[4]; bf16x8 v; } fa;
          fa.u[0] = x0; fa.u[1] = x1; fa.u[2] = y0; fa.u[3] = y1;
          const int ks = 2 * kb + b;   // k-slice 16*ks .. 16*ks+15
          #pragma unroll
          for (int db = 0; db < 2; ++db) {
            const int vrow = 32 * db + ql;
            bf16x8 vb = *(const bf16x8*)(vbuf + vrow * 128 +
                                         (((2*ks + h) ^ (vrow & 7)) << 4));
            acc[db] = __builtin_amdgcn_mfma_f32_32x32x16_bf16(fa.v, vb, acc[db], 0, 0, 0);
          }
        }
      }
    }

    kmod += 1; if (kmod == 3) kmod = 0;
  }

  // ---- epilogue: cross-half l-sum, redistribute rcp to C rows, store ----
  float tot = lsum + __shfl_xor(lsum, 32, 64);
  float rcp = 1.0f / tot;              // valid for query lo+ql
  float rr[16];
  #pragma unroll
  for (int r = 0; r < 16; ++r)
    rr[r] = __shfl(rcp, ((r & 3) + 8 * (r >> 2)) + 4 * h, 64);
  #pragma unroll
  for (int db = 0; db < 2; ++db)
    #pragma unroll
    for (int r = 0; r < 16; ++r) {
      const int row = lo + ((r & 3) + 8 * (r >> 2)) + 4 * h;
      Og[base + (size_t)row * DH + 32 * db + ql] = acc[db][r] * rr[r];
    }
}

// ---------------------------------------------------------------------------
// Fallback (fp32 inputs, self-contained) if workspace too small.
// ---------------------------------------------------------------------------
#define LDP 72
__global__ __launch_bounds__(256) void swa_attn_fallback(
    const float* __restrict__ Qg, const float* __restrict__ Kg,
    const float* __restrict__ Vg, float* __restrict__ Og)
{
  const int qt = blockIdx.x, bh = blockIdx.y;
  const int q0 = qt * 64;
  const size_t base = (size_t)bh * SEQ * DH;
  const int t = threadIdx.x, w = t >> 6, l = t & 63, quad = l >> 4, lc = l & 15;

  __shared__ unsigned short Qs[64][LDP];
  __shared__ unsigned short KsF[64][LDP];
  __shared__ unsigned short VtF[DH][LDP];
  __shared__ unsigned short PsF[4][16][LDP];

  {
    const float* src = Qg + base + (size_t)q0 * DH;
    #pragma unroll
    for (int i = 0; i < 4; ++i) {
      int e = t + 256 * i, row = e >> 4, d4 = (e & 15) * 4;
      float4 v = *(const float4*)(src + row * DH + d4);
      ushort4 o; o.x=f2bf(v.x*0.125f); o.y=f2bf(v.y*0.125f); o.z=f2bf(v.z*0.125f); o.w=f2bf(v.w*0.125f);
      *(ushort4*)&Qs[row][d4] = o;
    }
  }
  __syncthreads();
  bf16x8 aq0 = *(const bf16x8*)&Qs[16*w+lc][0 + 8*quad];
  bf16x8 aq1 = *(const bf16x8*)&Qs[16*w+lc][32 + 8*quad];

  float lsum[4]; f32x4 acc_o[4];
  #pragma unroll
  for (int r = 0; r < 4; ++r) lsum[r] = 0.0f;
  #pragma unroll
  for (int g = 0; g < 4; ++g) { acc_o[g][0]=0.f; acc_o[g][1]=0.f; acc_o[g][2]=0.f; acc_o[g][3]=0.f; }
  const int kt_lo = (qt - 8 > 0) ? (qt - 8) : 0;

  for (int kt = qt; kt >= kt_lo; --kt) {
    const int k0 = kt * 64;
    __syncthreads();
    {
      const float* srcK = Kg + base + (size_t)k0 * DH;
      const float* srcV = Vg + base + (size_t)k0 * DH;
      #pragma unroll
      for (int i = 0; i < 4; ++i) {
        int e = t + 256 * i, row = e >> 4, d4 = (e & 15) * 4;
        float4 kv = *(const float4*)(srcK + row * DH + d4);
        ushort4 ko; ko.x=f2bf(kv.x); ko.y=f2bf(kv.y); ko.z=f2bf(kv.z); ko.w=f2bf(kv.w);
        *(ushort4*)&KsF[row][d4] = ko;
        float4 vv = *(const float4*)(srcV + row * DH + d4);
        VtF[d4+0][row]=f2bf(vv.x); VtF[d4+1][row]=f2bf(vv.y);
        VtF[d4+2][row]=f2bf(vv.z); VtF[d4+3][row]=f2bf(vv.w);
      }
    }
    __syncthreads();

    f32x4 sc[4];
    #pragma unroll
    for (int g = 0; g < 4; ++g) {
      bf16x8 b0 = *(const bf16x8*)&KsF[16*g+lc][0 + 8*quad];
      bf16x8 b1 = *(const bf16x8*)&KsF[16*g+lc][32 + 8*quad];
      f32x4 c; c[0]=0.f; c[1]=0.f; c[2]=0.f; c[3]=0.f;
      c = __builtin_amdgcn_mfma_f32_16x16x32_bf16(aq0, b0, c, 0, 0, 0);
      c = __builtin_amdgcn_mfma_f32_16x16x32_bf16(aq1, b1, c, 0, 0, 0);
      sc[g] = c;
    }
    const int dbase = (k0 + lc) - (q0 + 16*w + 4*quad);
    #pragma unroll
    for (int g = 0; g < 4; ++g)
      #pragma unroll
      for (int r = 0; r < 4; ++r) {
        int dji = dbase + 16*g - r;
        float s = sc[g][r];
        s = (dji <= 0 && dji >= -(WIN-1)) ? s : -1e30f;
        float e = __expf(s);
        lsum[r] += e;
        PsF[w][4*quad+r][16*g+lc] = f2bf(e);
      }
    __asm__ __volatile__("s_waitcnt lgkmcnt(0)" ::: "memory");
    bf16x8 pa0 = *(const bf16x8*)&PsF[w][lc][0 + 8*quad];
    bf16x8 pa1 = *(const bf16x8*)&PsF[w][lc][32 + 8*quad];
    #pragma unroll
    for (int gn = 0; gn < 4; ++gn) {
      bf16x8 vb0 = *(const bf16x8*)&VtF[16*gn+lc][0 + 8*quad];
      bf16x8 vb1 = *(const bf16x8*)&VtF[16*gn+lc][32 + 8*quad];
      f32x4 c = acc_o[gn];
      c = __builtin_amdgcn_mfma_f32_16x16x32_bf16(pa0, vb0, c, 0, 0, 0);
      c = __builtin_amdgcn_mfma_f32_16x16x32_bf16(pa1, vb1, c, 0, 0, 0);
      acc_o[gn] = c;
    }
  }
  #pragma unroll
  for (int off = 1; off < 16; off <<= 1)
    #pragma unroll
    for (int r = 0; r < 4; ++r)
      lsum[r] += __shfl_xor(lsum[r], off, 64);
  #pragma unroll
  for (int gn = 0; gn < 4; ++gn)
    #pragma unroll
    for (int r = 0; r < 4; ++r) {
      int row = q0 + 16*w + 4*quad + r;
      Og[base + (size_t)row * DH + 16*gn + lc] = acc_o[gn][r] / lsum[r];
    }
}

extern "C" void kernel_launch(void* const* d_in, const int* in_sizes, int n_in,
                              void* d_out, int out_size, void* d_ws, size_t ws_size,
                              hipStream_t stream) {
  const float* Q = (const float*)d_in[0];
  const float* K = (const float*)d_in[1];
  const float* V = (const float*)d_in[2];
  float* O = (float*)d_out;

  const size_t kbytes = (size_t)NBATCH * NHEAD * SEQ * DH * 2;   // 8 MB
  if (ws_size >= 2 * kbytes) {
    ushort_t* Kw = (ushort_t*)d_ws;
    ushort_t* Vw = (ushort_t*)((char*)d_ws + kbytes);
    prep_kernel<<<dim3(SEQ / KT, NBATCH * NHEAD), dim3(256), 0, stream>>>(K, V, Kw, Vw);
    swa_attn_kernel<<<dim3(SEQ / QT, NBATCH * NHEAD), dim3(256), 0, stream>>>(Q, Kw, Vw, O);
  } else {
    swa_attn_fallback<<<dim3(SEQ / 64, NBATCH * NHEAD), dim3(256), 0, stream>>>(Q, K, V, O);
  }
}

// Round 2
// 110.975 us; speedup vs baseline: 1.0130x; 1.0033x over previous
//
#include <hip/hip_runtime.h>

// Sliding-window causal attention, B=2 H=8 S=4096 D=64, window=512.
// R7: R6 structure (32-query waves, swapped QK^T, in-register P transpose)
//  + 2-tile-deep prefetch: K AND V triple-buffered, tile i+2 issued each
//    iteration, single s_waitcnt vmcnt(4) per tile (never 0 mid-loop).
//  + bijective XCD swizzle: each XCD owns 2 bh panels (2 MB, fits its L2).
//  + exp2-folded scale (log2e baked into Q prescale) + tree l-sum.

#define NBATCH 2
#define NHEAD  8
#define SEQ    4096
#define DH     64
#define WIN    512
#define QT     128
#define KT     64

typedef __attribute__((ext_vector_type(4)))  float f32x4;
typedef __attribute__((ext_vector_type(16))) float f32x16;
typedef __attribute__((ext_vector_type(8)))  short bf16x8;
typedef unsigned short ushort_t;

__device__ __forceinline__ unsigned short f2bf(float f) {
  unsigned u = __builtin_bit_cast(unsigned, f);
  u += 0x7fffu + ((u >> 16) & 1u);
  return (unsigned short)(u >> 16);
}

__device__ __forceinline__ unsigned pkbf16(float a, float b) {
  unsigned d;
  asm("v_cvt_pk_bf16_f32 %0, %1, %2" : "=v"(d) : "v"(a), "v"(b));
  return d;
}

#define GLD16(gp, lp)                                                          \
  __builtin_amdgcn_global_load_lds(                                            \
      (const __attribute__((address_space(1))) unsigned int*)(gp),             \
      (__attribute__((address_space(3))) unsigned int*)(lp), 16, 0, 0)

// ---------------------------------------------------------------------------
// Prep: swizzled 8 KB 64x64 tile images. (row,blk) -> row*128 + ((blk^(row&7))<<4)
// K image: row = key, blk = d/8.   V image: row = d, blk = key/8.
// ---------------------------------------------------------------------------
__global__ __launch_bounds__(256) void prep_kernel(
    const float* __restrict__ Kg, const float* __restrict__ Vg,
    ushort_t* __restrict__ Kw, ushort_t* __restrict__ Vw)
{
  const int kt = blockIdx.x, bh = blockIdx.y;
  const size_t gbase = (size_t)bh * SEQ * DH + (size_t)kt * KT * DH;
  const size_t tbyte = ((size_t)bh * 64 + kt) * 8192;
  const int t = threadIdx.x;

  __shared__ float Vs[64][65];

  #pragma unroll
  for (int c = 0; c < 2; ++c) {
    int u = t + 256 * c, row = u >> 3, blk = u & 7;
    const float* src = Kg + gbase + row * DH + blk * 8;
    float4 a = *(const float4*)src;
    float4 b = *(const float4*)(src + 4);
    union { unsigned short us[8]; uint4 q; } o;
    o.us[0]=f2bf(a.x); o.us[1]=f2bf(a.y); o.us[2]=f2bf(a.z); o.us[3]=f2bf(a.w);
    o.us[4]=f2bf(b.x); o.us[5]=f2bf(b.y); o.us[6]=f2bf(b.z); o.us[7]=f2bf(b.w);
    *(uint4*)((char*)Kw + tbyte + row * 128 + ((blk ^ (row & 7)) << 4)) = o.q;
  }

  #pragma unroll
  for (int i = 0; i < 4; ++i) {
    int e = t + 256 * i, row = e >> 4, c4 = (e & 15) * 4;
    float4 v = *(const float4*)(Vg + gbase + row * DH + c4);
    Vs[row][c4 + 0] = v.x; Vs[row][c4 + 1] = v.y;
    Vs[row][c4 + 2] = v.z; Vs[row][c4 + 3] = v.w;
  }
  __syncthreads();

  #pragma unroll
  for (int c = 0; c < 2; ++c) {
    int u = t + 256 * c, d = u >> 3, blk = u & 7;
    union { unsigned short us[8]; uint4 q; } o;
    #pragma unroll
    for (int j = 0; j < 8; ++j) o.us[j] = f2bf(Vs[blk * 8 + j][d]);
    *(uint4*)((char*)Vw + tbyte + d * 128 + ((blk ^ (d & 7)) << 4)) = o.q;
  }
}

// ---------------------------------------------------------------------------
// Attention: one block = 128 queries of one (b,h); 4 waves x 32 queries.
// ---------------------------------------------------------------------------
__global__ __launch_bounds__(256, 2) void swa_attn_kernel(
    const float* __restrict__ Qg, const ushort_t* __restrict__ Kw,
    const ushort_t* __restrict__ Vw, float* __restrict__ Og)
{
  // bijective XCD swizzle: 512 blocks, 8 XCDs, 64 blocks/XCD = 2 bh panels.
  // XCD-local Kw/Vw working set = 2 MB -> fits the 4 MB per-XCD L2.
  const int flat = blockIdx.y * gridDim.x + blockIdx.x;      // 0..511
  const int swz  = (flat & 7) * 64 + (flat >> 3);
  const int qt = swz & 31, bh = swz >> 5;

  const int q0 = qt * QT;
  const size_t base = (size_t)bh * SEQ * DH;
  const int t = threadIdx.x, w = t >> 6, l = t & 63;
  const int ql = l & 31, h = l >> 5;

  __shared__ ushort_t Ks[3][4096];   // 24 KB, triple buffer
  __shared__ ushort_t Vt[3][4096];   // 24 KB, triple buffer
  // total 48 KB -> 2 blocks/CU (grid is exactly 2/CU)

  const size_t tile0 = ((size_t)bh * 64) * 8192;
  const int ldoff = w * 2048;        // this wave's 2 KB slice (wave-uniform)

  auto issueK = [&](int b, int kt) {
    const char* g = (const char*)Kw + tile0 + (size_t)kt * 8192 + ldoff;
    char* lp = (char*)&Ks[b][0] + ldoff;
    GLD16(g + l * 16, lp);
    GLD16(g + 1024 + l * 16, lp + 1024);
  };
  auto issueV = [&](int b, int kt) {
    const char* g = (const char*)Vw + tile0 + (size_t)kt * 8192 + ldoff;
    char* lp = (char*)&Vt[b][0] + ldoff;
    GLD16(g + l * 16, lp);
    GLD16(g + 1024 + l * 16, lp + 1024);
  };

  const int kt_hi = 2 * qt + 1;
  const int kt_lo = (2 * qt - 8 > 0) ? (2 * qt - 8) : 0;
  const int NT = kt_hi - kt_lo + 1;   // >= 2 always

  const int lo = q0 + 32 * w;   // this wave's min query row
  const int hi = lo + 31;       // max query row

  // ---- Q loads FIRST (oldest in vmcnt queue) ----
  const float* qrow = Qg + base + (size_t)(lo + ql) * DH;
  float4 qa[4], qb[4];
  #pragma unroll
  for (int tf = 0; tf < 4; ++tf) {
    qa[tf] = *(const float4*)(qrow + 16 * tf + 8 * h);
    qb[tf] = *(const float4*)(qrow + 16 * tf + 8 * h + 4);
  }
  issueK(0, kt_hi);
  issueV(0, kt_hi);

  // Q as B-frags, prescaled by (1/8)*log2(e) so softmax is raw v_exp_f32.
  const float QS = 0.125f * 1.44269504088896f;
  bf16x8 aq[4];
  #pragma unroll
  for (int tf = 0; tf < 4; ++tf) {
    union { unsigned short us[8]; bf16x8 v; } u;
    u.us[0]=f2bf(qa[tf].x*QS); u.us[1]=f2bf(qa[tf].y*QS);
    u.us[2]=f2bf(qa[tf].z*QS); u.us[3]=f2bf(qa[tf].w*QS);
    u.us[4]=f2bf(qb[tf].x*QS); u.us[5]=f2bf(qb[tf].y*QS);
    u.us[6]=f2bf(qb[tf].z*QS); u.us[7]=f2bf(qb[tf].w*QS);
    aq[tf] = u.v;
  }

  // second prefetch tile (2-deep pipeline)
  issueK(1, kt_hi - 1);
  issueV(1, kt_hi - 1);

  f32x16 acc[2];
  #pragma unroll
  for (int db = 0; db < 2; ++db)
    #pragma unroll
    for (int r = 0; r < 16; ++r) acc[db][r] = 0.0f;
  float lsum = 0.0f;

  int cur = 0;  // i % 3
  for (int i = 0; i < NT; ++i) {
    const int kt = kt_hi - i;
    const int k0 = kt * KT;

    // Drain tile i's K+V (4 oldest); leave tile i+1's 4 loads in flight.
    if (i < NT - 1) {
      __asm__ __volatile__("s_waitcnt vmcnt(4)\n\ts_barrier" ::: "memory");
    } else {
      __asm__ __volatile__("s_waitcnt vmcnt(0)\n\ts_barrier" ::: "memory");
    }
    // Issue tile i+2 AFTER the barrier: buffer (i+2)%3 == (i-1)%3 was fully
    // consumed by all waves before they reached this barrier.
    if (i + 2 < NT) {
      int nxt = cur + 2; if (nxt >= 3) nxt -= 3;
      issueK(nxt, kt - 2);
      issueV(nxt, kt - 2);
    }

    // ---- per-wave skip of fully-masked tiles (wave-uniform branch) ----
    const bool active = (k0 <= hi) && (k0 + KT - 1 >= lo - (WIN - 1));
    if (active) {
      const char* kbuf = (const char*)&Ks[cur][0];
      const char* vbuf = (const char*)&Vt[cur][0];

      // ---- S^T = K Q^T : lane holds P[k = 32*kb + a(r) + 4h][q = lo+ql] ----
      f32x16 p[2];
      #pragma unroll
      for (int kb = 0; kb < 2; ++kb) {
        const int krow = 32 * kb + ql;
        const int ksz = krow & 7;
        f32x16 c;
        #pragma unroll
        for (int r = 0; r < 16; ++r) c[r] = 0.0f;
        #pragma unroll
        for (int tf = 0; tf < 4; ++tf) {
          bf16x8 ka = *(const bf16x8*)(kbuf + krow * 128 + (((2*tf + h) ^ ksz) << 4));
          c = __builtin_amdgcn_mfma_f32_32x32x16_bf16(ka, aq[tf], c, 0, 0, 0);
        }
        p[kb] = c;
      }

      // ---- exp2 (m=0 fixed shift, exact) + tree-reduced l-sum ----
      const int dbase = k0 - (lo + ql) + 4 * h;
      const bool needmask = (k0 + KT - 1 > lo) || (k0 < hi - (WIN - 1));
      float ps0 = 0.f, ps1 = 0.f, ps2 = 0.f, ps3 = 0.f;
      if (needmask) {
        #pragma unroll
        for (int kb = 0; kb < 2; ++kb)
          #pragma unroll
          for (int r = 0; r < 16; ++r) {
            const int dji = dbase + 32 * kb + ((r & 3) + 8 * (r >> 2));
            float s = ((unsigned)(dji + (WIN - 1)) <= (unsigned)(WIN - 1))
                          ? p[kb][r] : -1e30f;
            float e = __builtin_amdgcn_exp2f(s);
            p[kb][r] = e;
            if ((r & 3) == 0) ps0 += e;
            else if ((r & 3) == 1) ps1 += e;
            else if ((r & 3) == 2) ps2 += e;
            else ps3 += e;
          }
      } else {
        #pragma unroll
        for (int kb = 0; kb < 2; ++kb)
          #pragma unroll
          for (int r = 0; r < 16; ++r) {
            float e = __builtin_amdgcn_exp2f(p[kb][r]);
            p[kb][r] = e;
            if ((r & 3) == 0) ps0 += e;
            else if ((r & 3) == 1) ps1 += e;
            else if ((r & 3) == 2) ps2 += e;
            else ps3 += e;
          }
      }
      lsum += (ps0 + ps1) + (ps2 + ps3);

      // ---- in-register P transpose -> A-frags, fused with O += P V ----
      #pragma unroll
      for (int kb = 0; kb < 2; ++kb) {
        #pragma unroll
        for (int b = 0; b < 2; ++b) {
          unsigned x0 = pkbf16(p[kb][8*b+0], p[kb][8*b+1]);
          unsigned x1 = pkbf16(p[kb][8*b+2], p[kb][8*b+3]);
          unsigned y0 = pkbf16(p[kb][8*b+4], p[kb][8*b+5]);
          unsigned y1 = pkbf16(p[kb][8*b+6], p[kb][8*b+7]);
          asm("v_permlane32_swap_b32 %0, %1" : "+v"(x0), "+v"(y0));
          asm("v_permlane32_swap_b32 %0, %1" : "+v"(x1), "+v"(y1));
          union { unsigned u[4]; bf16x8 v; } fa;
          fa.u[0] = x0; fa.u[1] = x1; fa.u[2] = y0; fa.u[3] = y1;
          const int ks = 2 * kb + b;   // k-slice 16*ks .. 16*ks+15
          #pragma unroll
          for (int db = 0; db < 2; ++db) {
            const int vrow = 32 * db + ql;
            bf16x8 vb = *(const bf16x8*)(vbuf + vrow * 128 +
                                         (((2*ks + h) ^ (vrow & 7)) << 4));
            acc[db] = __builtin_amdgcn_mfma_f32_32x32x16_bf16(fa.v, vb, acc[db], 0, 0, 0);
          }
        }
      }
    }

    cur += 1; if (cur == 3) cur = 0;
  }

  // ---- epilogue: cross-half l-sum, redistribute rcp to C rows, store ----
  float tot = lsum + __shfl_xor(lsum, 32, 64);
  float rcp = 1.0f / tot;              // valid for query lo+ql
  float rr[16];
  #pragma unroll
  for (int r = 0; r < 16; ++r)
    rr[r] = __shfl(rcp, ((r & 3) + 8 * (r >> 2)) + 4 * h, 64);
  #pragma unroll
  for (int db = 0; db < 2; ++db)
    #pragma unroll
    for (int r = 0; r < 16; ++r) {
      const int row = lo + ((r & 3) + 8 * (r >> 2)) + 4 * h;
      Og[base + (size_t)row * DH + 32 * db + ql] = acc[db][r] * rr[r];
    }
}

// ---------------------------------------------------------------------------
// Fallback (fp32 inputs, self-contained) if workspace too small.
// ---------------------------------------------------------------------------
#define LDP 72
__global__ __launch_bounds__(256) void swa_attn_fallback(
    const float* __restrict__ Qg, const float* __restrict__ Kg,
    const float* __restrict__ Vg, float* __restrict__ Og)
{
  const int qt = blockIdx.x, bh = blockIdx.y;
  const int q0 = qt * 64;
  const size_t base = (size_t)bh * SEQ * DH;
  const int t = threadIdx.x, w = t >> 6, l = t & 63, quad = l >> 4, lc = l & 15;

  __shared__ unsigned short Qs[64][LDP];
  __shared__ unsigned short KsF[64][LDP];
  __shared__ unsigned short VtF[DH][LDP];
  __shared__ unsigned short PsF[4][16][LDP];

  {
    const float* src = Qg + base + (size_t)q0 * DH;
    #pragma unroll
    for (int i = 0; i < 4; ++i) {
      int e = t + 256 * i, row = e >> 4, d4 = (e & 15) * 4;
      float4 v = *(const float4*)(src + row * DH + d4);
      ushort4 o; o.x=f2bf(v.x*0.125f); o.y=f2bf(v.y*0.125f); o.z=f2bf(v.z*0.125f); o.w=f2bf(v.w*0.125f);
      *(ushort4*)&Qs[row][d4] = o;
    }
  }
  __syncthreads();
  bf16x8 aq0 = *(const bf16x8*)&Qs[16*w+lc][0 + 8*quad];
  bf16x8 aq1 = *(const bf16x8*)&Qs[16*w+lc][32 + 8*quad];

  float lsum[4]; f32x4 acc_o[4];
  #pragma unroll
  for (int r = 0; r < 4; ++r) lsum[r] = 0.0f;
  #pragma unroll
  for (int g = 0; g < 4; ++g) { acc_o[g][0]=0.f; acc_o[g][1]=0.f; acc_o[g][2]=0.f; acc_o[g][3]=0.f; }
  const int kt_lo = (qt - 8 > 0) ? (qt - 8) : 0;

  for (int kt = qt; kt >= kt_lo; --kt) {
    const int k0 = kt * 64;
    __syncthreads();
    {
      const float* srcK = Kg + base + (size_t)k0 * DH;
      const float* srcV = Vg + base + (size_t)k0 * DH;
      #pragma unroll
      for (int i = 0; i < 4; ++i) {
        int e = t + 256 * i, row = e >> 4, d4 = (e & 15) * 4;
        float4 kv = *(const float4*)(srcK + row * DH + d4);
        ushort4 ko; ko.x=f2bf(kv.x); ko.y=f2bf(kv.y); ko.z=f2bf(kv.z); ko.w=f2bf(kv.w);
        *(ushort4*)&KsF[row][d4] = ko;
        float4 vv = *(const float4*)(srcV + row * DH + d4);
        VtF[d4+0][row]=f2bf(vv.x); VtF[d4+1][row]=f2bf(vv.y);
        VtF[d4+2][row]=f2bf(vv.z); VtF[d4+3][row]=f2bf(vv.w);
      }
    }
    __syncthreads();

    f32x4 sc[4];
    #pragma unroll
    for (int g = 0; g < 4; ++g) {
      bf16x8 b0 = *(const bf16x8*)&KsF[16*g+lc][0 + 8*quad];
      bf16x8 b1 = *(const bf16x8*)&KsF[16*g+lc][32 + 8*quad];
      f32x4 c; c[0]=0.f; c[1]=0.f; c[2]=0.f; c[3]=0.f;
      c = __builtin_amdgcn_mfma_f32_16x16x32_bf16(aq0, b0, c, 0, 0, 0);
      c = __builtin_amdgcn_mfma_f32_16x16x32_bf16(aq1, b1, c, 0, 0, 0);
      sc[g] = c;
    }
    const int dbase = (k0 + lc) - (q0 + 16*w + 4*quad);
    #pragma unroll
    for (int g = 0; g < 4; ++g)
      #pragma unroll
      for (int r = 0; r < 4; ++r) {
        int dji = dbase + 16*g - r;
        float s = sc[g][r];
        s = (dji <= 0 && dji >= -(WIN-1)) ? s : -1e30f;
        float e = __expf(s);
        lsum[r] += e;
        PsF[w][4*quad+r][16*g+lc] = f2bf(e);
      }
    __asm__ __volatile__("s_waitcnt lgkmcnt(0)" ::: "memory");
    bf16x8 pa0 = *(const bf16x8*)&PsF[w][lc][0 + 8*quad];
    bf16x8 pa1 = *(const bf16x8*)&PsF[w][lc][32 + 8*quad];
    #pragma unroll
    for (int gn = 0; gn < 4; ++gn) {
      bf16x8 vb0 = *(const bf16x8*)&VtF[16*gn+lc][0 + 8*quad];
      bf16x8 vb1 = *(const bf16x8*)&VtF[16*gn+lc][32 + 8*quad];
      f32x4 c = acc_o[gn];
      c = __builtin_amdgcn_mfma_f32_16x16x32_bf16(pa0, vb0, c, 0, 0, 0);
      c = __builtin_amdgcn_mfma_f32_16x16x32_bf16(pa1, vb1, c, 0, 0, 0);
      acc_o[gn] = c;
    }
  }
  #pragma unroll
  for (int off = 1; off < 16; off <<= 1)
    #pragma unroll
    for (int r = 0; r < 4; ++r)
      lsum[r] += __shfl_xor(lsum[r], off, 64);
  #pragma unroll
  for (int gn = 0; gn < 4; ++gn)
    #pragma unroll
    for (int r = 0; r < 4; ++r) {
      int row = q0 + 16*w + 4*quad + r;
      Og[base + (size_t)row * DH + 16*gn + lc] = acc_o[gn][r] / lsum[r];
    }
}

extern "C" void kernel_launch(void* const* d_in, const int* in_sizes, int n_in,
                              void* d_out, int out_size, void* d_ws, size_t ws_size,
                              hipStream_t stream) {
  const float* Q = (const float*)d_in[0];
  const float* K = (const float*)d_in[1];
  const float* V = (const float*)d_in[2];
  float* O = (float*)d_out;

  const size_t kbytes = (size_t)NBATCH * NHEAD * SEQ * DH * 2;   // 8 MB
  if (ws_size >= 2 * kbytes) {
    ushort_t* Kw = (ushort_t*)d_ws;
    ushort_t* Vw = (ushort_t*)((char*)d_ws + kbytes);
    prep_kernel<<<dim3(SEQ / KT, NBATCH * NHEAD), dim3(256), 0, stream>>>(K, V, Kw, Vw);
    swa_attn_kernel<<<dim3(SEQ / QT, NBATCH * NHEAD), dim3(256), 0, stream>>>(Q, Kw, Vw, O);
  } else {
    swa_attn_fallback<<<dim3(SEQ / 64, NBATCH * NHEAD), dim3(256), 0, stream>>>(Q, K, V, O);
  }
}